// Round 1
// baseline (455.142 us; speedup 1.0000x reference)
//
#include <hip/hip_runtime.h>
#include <hip/hip_bf16.h>
#include <math.h>

#define C_DIM 192
#define NTOK 16384
#define NB 16
#define NH 8
#define HD 24
#define EPSN 1e-12f

typedef float f32x4 __attribute__((ext_vector_type(4)));
typedef __bf16 bf16x8 __attribute__((ext_vector_type(8)));

__device__ __forceinline__ f32x4 mfma16(bf16x8 a, bf16x8 b, f32x4 c) {
  return __builtin_amdgcn_mfma_f32_16x16x32_bf16(a, b, c, 0, 0, 0);
}

// load 8 consecutive f32 (16B-aligned x2) and convert to 8 bf16
__device__ __forceinline__ bf16x8 cvt8(const float* __restrict__ p) {
  f32x4 a = *(const f32x4*)p;
  f32x4 b = *(const f32x4*)(p + 4);
  bf16x8 r;
  r[0] = (__bf16)a[0]; r[1] = (__bf16)a[1]; r[2] = (__bf16)a[2]; r[3] = (__bf16)a[3];
  r[4] = (__bf16)b[0]; r[5] = (__bf16)b[1]; r[6] = (__bf16)b[2]; r[7] = (__bf16)b[3];
  return r;
}

// ---------------- K1: partial Gram  Gpart[chunk][b] = x_slice @ x_slice^T ----
__global__ __launch_bounds__(256, 2) void k1_gram(const float* __restrict__ x,
                                                  float* __restrict__ gpart,
                                                  int kc) {
  const int b = blockIdx.y, chunk = blockIdx.x;
  const float* xb = x + (size_t)b * C_DIM * NTOK + (size_t)chunk * kc;
  const int lane = threadIdx.x & 63, wid = threadIdx.x >> 6;
  const int lrow = lane & 15, loct = lane >> 4;
  const int r0 = (wid >> 1) * 96, c0 = (wid & 1) * 96;
  f32x4 acc[6][6] = {};
  for (int ks = 0; ks < kc; ks += 32) {
    bf16x8 fa[6], fb[6];
#pragma unroll
    for (int i = 0; i < 6; ++i)
      fa[i] = cvt8(xb + (size_t)(r0 + 16 * i + lrow) * NTOK + ks + 8 * loct);
#pragma unroll
    for (int j = 0; j < 6; ++j)
      fb[j] = cvt8(xb + (size_t)(c0 + 16 * j + lrow) * NTOK + ks + 8 * loct);
#pragma unroll
    for (int i = 0; i < 6; ++i)
#pragma unroll
      for (int j = 0; j < 6; ++j)
        acc[i][j] = mfma16(fa[i], fb[j], acc[i][j]);
  }
  float* gp = gpart + ((size_t)chunk * NB + b) * C_DIM * C_DIM;
#pragma unroll
  for (int i = 0; i < 6; ++i)
#pragma unroll
    for (int j = 0; j < 6; ++j)
#pragma unroll
      for (int e = 0; e < 4; ++e)
        gp[(size_t)(r0 + 16 * i + 4 * loct + e) * C_DIM + (c0 + 16 * j + lrow)] =
            acc[i][j][e];
}

// ---------------- K2a: reduce partials -> G ---------------------------------
__global__ __launch_bounds__(256) void k2a_reduce(const float* __restrict__ gpart,
                                                  float* __restrict__ G,
                                                  int nchunk) {
  const size_t total = (size_t)NB * C_DIM * C_DIM;
  size_t e0 = ((size_t)blockIdx.x * 256 + threadIdx.x) * 4;
  f32x4 s = {};
  for (int c = 0; c < nchunk; ++c) s += *(const f32x4*)(gpart + c * total + e0);
  *(f32x4*)(G + e0) = s;
}

// ---------------- K2b1: Tt[b] = [Wq|Wk]^T @ G  (384x192), uses G symmetry ---
__global__ __launch_bounds__(256) void k2b1_t(const float* __restrict__ G,
                                              const float* __restrict__ wqkv,
                                              float* __restrict__ Tt) {
  const int b = blockIdx.y, rb = blockIdx.x;  // rb 0..5 -> 64 rows
  const int lane = threadIdx.x & 63, wid = threadIdx.x >> 6;
  const int lrow = lane & 15, loct = lane >> 4;
  const float* Gb = G + (size_t)b * C_DIM * C_DIM;
  const int ddA = rb * 64 + wid * 16 + lrow;  // < 384, == wqkv column index
  f32x4 acc[12] = {};
  for (int s = 0; s < 6; ++s) {
    bf16x8 fa;
#pragma unroll
    for (int e = 0; e < 8; ++e)
      fa[e] = (__bf16)wqkv[(size_t)(32 * s + 8 * loct + e) * 576 + ddA];
#pragma unroll
    for (int j = 0; j < 12; ++j) {
      bf16x8 fb = cvt8(Gb + (size_t)(16 * j + lrow) * C_DIM + 32 * s + 8 * loct);
      acc[j] = mfma16(fa, fb, acc[j]);
    }
  }
  float* To = Tt + (size_t)b * 384 * C_DIM;
#pragma unroll
  for (int j = 0; j < 12; ++j)
#pragma unroll
    for (int e = 0; e < 4; ++e)
      To[(size_t)(rb * 64 + wid * 16 + 4 * loct + e) * C_DIM + 16 * j + lrow] =
          acc[j][e];
}

// ---------------- K2b2: per (b,h): S, norms, softmax, Yt -------------------
__global__ __launch_bounds__(256) void k2b2_attn(const float* __restrict__ Tt,
                                                 const float* __restrict__ wqkv,
                                                 const float* __restrict__ temp,
                                                 float* __restrict__ Yt) {
  const int b = blockIdx.y, h = blockIdx.x;
  __shared__ float SL[32][33];
  __shared__ float qn2L[HD], kn2L[HD];
  const int t = threadIdx.x;
  const int lane = t & 63, wid = t >> 6;
  const int lrow = lane & 15, loct = lane >> 4;
  const float* Tb = Tt + (size_t)b * 384 * C_DIM;
  const int r = wid >> 1, j = wid & 1;  // 2x2 tiles cover 32x32 (clip to 24x24)
  f32x4 acc = {};
  for (int s = 0; s < 6; ++s) {
    bf16x8 fa = cvt8(Tb + (size_t)(h * HD + 16 * r + lrow) * C_DIM + 32 * s + 8 * loct);
    bf16x8 fb;
#pragma unroll
    for (int e = 0; e < 8; ++e)
      fb[e] = (__bf16)wqkv[(size_t)(32 * s + 8 * loct + e) * 576 + 192 + h * HD +
                           16 * j + lrow];
    acc = mfma16(fa, fb, acc);
  }
#pragma unroll
  for (int e = 0; e < 4; ++e) {
    int d = 16 * r + 4 * loct + e, ee = 16 * j + lrow;
    if (d < HD && ee < HD) SL[d][ee] = acc[e];
  }
  if (t < 48) {  // squared norms: diag of Wq^T G Wq / Wk^T G Wk
    const int dd = (t < 24) ? t : t - 24;
    const int row = ((t < 24) ? 0 : 192) + h * HD + dd;
    float s = 0.f;
    for (int c = 0; c < C_DIM; ++c)
      s += Tb[(size_t)row * C_DIM + c] * wqkv[(size_t)c * 576 + row];
    if (t < 24) qn2L[dd] = s; else kn2L[dd] = s;
  }
  __syncthreads();
  if (t < HD) {  // softmax row t
    const float tp = temp[h];
    float nq = fmaxf(sqrtf(fmaxf(qn2L[t], 0.f)), EPSN);
    float lg[HD];
    float m = -1e30f;
#pragma unroll
    for (int e = 0; e < HD; ++e) {
      float nk = fmaxf(sqrtf(fmaxf(kn2L[e], 0.f)), EPSN);
      lg[e] = SL[t][e] / (nq * nk) * tp;
      m = fmaxf(m, lg[e]);
    }
    float sum = 0.f;
#pragma unroll
    for (int e = 0; e < HD; ++e) { lg[e] = __expf(lg[e] - m); sum += lg[e]; }
    float inv = 1.f / sum;
#pragma unroll
    for (int e = 0; e < HD; ++e) SL[t][e] = lg[e] * inv;
  }
  __syncthreads();
  if (t < C_DIM) {  // Yt[b][ci=t][h*24+d] = sum_e attn[d][e] * Wv[t][e]
    float wv[HD];
#pragma unroll
    for (int e = 0; e < HD; ++e)
      wv[e] = wqkv[(size_t)t * 576 + 384 + h * HD + e];
    float* Yo = Yt + ((size_t)b * C_DIM + t) * C_DIM + h * HD;
#pragma unroll
    for (int d = 0; d < HD; ++d) {
      float y = 0.f;
#pragma unroll
      for (int e = 0; e < HD; ++e) y += SL[d][e] * wv[e];
      Yo[d] = y;
    }
  }
}

// ---------------- K2c: M[b] = Wproj^T @ Y  (bf16 out) -----------------------
__global__ __launch_bounds__(256) void k2c_m(const float* __restrict__ wproj,
                                             const float* __restrict__ Yt,
                                             __bf16* __restrict__ M) {
  const int b = blockIdx.y, rb = blockIdx.x;  // rb 0..2 -> 64 rows
  const int lane = threadIdx.x & 63, wid = threadIdx.x >> 6;
  const int lrow = lane & 15, loct = lane >> 4;
  const float* Yb = Yt + (size_t)b * C_DIM * C_DIM;
  const int coA = rb * 64 + wid * 16 + lrow;
  f32x4 acc[12] = {};
  for (int s = 0; s < 6; ++s) {
    bf16x8 fa;
#pragma unroll
    for (int e = 0; e < 8; ++e)
      fa[e] = (__bf16)wproj[(size_t)(32 * s + 8 * loct + e) * C_DIM + coA];
#pragma unroll
    for (int j = 0; j < 12; ++j) {
      bf16x8 fb = cvt8(Yb + (size_t)(16 * j + lrow) * C_DIM + 32 * s + 8 * loct);
      acc[j] = mfma16(fa, fb, acc[j]);
    }
  }
  __bf16* Mo = M + (size_t)b * C_DIM * C_DIM;
#pragma unroll
  for (int j = 0; j < 12; ++j)
#pragma unroll
    for (int e = 0; e < 4; ++e)
      Mo[(size_t)(rb * 64 + wid * 16 + 4 * loct + e) * C_DIM + 16 * j + lrow] =
          (__bf16)acc[j][e];
}

// ---------------- K3: out[b] = M[b] @ x[b] + bias ---------------------------
__global__ __launch_bounds__(256, 2) void k3_out(const float* __restrict__ x,
                                                 const __bf16* __restrict__ M,
                                                 const float* __restrict__ bproj,
                                                 float* __restrict__ out) {
  const int b = blockIdx.y, nt = blockIdx.x;
  __shared__ __bf16 Ml[C_DIM * C_DIM];  // 72KB, 16B-chunk XOR swizzle
  __shared__ float biasL[C_DIM];
  const __bf16* Mb = M + (size_t)b * C_DIM * C_DIM;
  for (int i = threadIdx.x; i < (C_DIM * C_DIM / 8); i += 256) {
    int row = i / 24, ch = i % 24;
    bf16x8 v = *(const bf16x8*)(Mb + row * C_DIM + ch * 8);
    *(bf16x8*)(Ml + row * C_DIM + ((ch ^ (row & 7)) * 8)) = v;
  }
  if (threadIdx.x < C_DIM) biasL[threadIdx.x] = bproj[threadIdx.x];
  __syncthreads();
  const int lane = threadIdx.x & 63, wid = threadIdx.x >> 6;
  const int lrow = lane & 15, loct = lane >> 4;
  const float* xb = x + (size_t)b * C_DIM * NTOK;
  float* ob = out + (size_t)b * C_DIM * NTOK;
  const int nbase = nt * 256 + wid * 64;
  for (int pair = 0; pair < 2; ++pair) {
    const int n0 = nbase + pair * 32;
    f32x4 acc[12][2] = {};
#pragma unroll
    for (int s = 0; s < 6; ++s) {
      bf16x8 fb0, fb1;
#pragma unroll
      for (int e = 0; e < 8; ++e) {
        size_t rowoff = (size_t)(32 * s + 8 * loct + e) * NTOK;
        fb0[e] = (__bf16)xb[rowoff + n0 + lrow];
        fb1[e] = (__bf16)xb[rowoff + n0 + 16 + lrow];
      }
#pragma unroll
      for (int tt = 0; tt < 12; ++tt) {
        int rowb = 16 * tt + lrow;
        bf16x8 fa = *(const bf16x8*)(Ml + rowb * C_DIM +
                                     (((4 * s + loct) ^ (rowb & 7)) * 8));
        acc[tt][0] = mfma16(fa, fb0, acc[tt][0]);
        acc[tt][1] = mfma16(fa, fb1, acc[tt][1]);
      }
    }
#pragma unroll
    for (int tt = 0; tt < 12; ++tt) {
      const int rw = 16 * tt + 4 * loct;
      f32x4 bias = *(const f32x4*)(biasL + rw);
#pragma unroll
      for (int e = 0; e < 4; ++e) {
        ob[(size_t)(rw + e) * NTOK + n0 + lrow] = acc[tt][0][e] + bias[e];
        ob[(size_t)(rw + e) * NTOK + n0 + 16 + lrow] = acc[tt][1][e] + bias[e];
      }
    }
  }
}

extern "C" void kernel_launch(void* const* d_in, const int* in_sizes, int n_in,
                              void* d_out, int out_size, void* d_ws, size_t ws_size,
                              hipStream_t stream) {
  const float* x = (const float*)d_in[0];
  const float* wqkv = (const float*)d_in[1];
  const float* wproj = (const float*)d_in[2];
  const float* bproj = (const float*)d_in[3];
  const float* temp = (const float*)d_in[4];
  float* out = (float*)d_out;

  const size_t GSZ = (size_t)NB * C_DIM * C_DIM;  // 589824 floats
  const size_t TSZ = (size_t)NB * 384 * C_DIM;    // 1179648 floats
  int nchunk = 16;
  while (nchunk > 1 &&
         ((size_t)nchunk * GSZ + GSZ + TSZ + GSZ + GSZ) * 4 > ws_size)
    nchunk >>= 1;
  float* wsf = (float*)d_ws;
  float* gpart = wsf;
  float* G = gpart + (size_t)nchunk * GSZ;
  float* Tt = G + GSZ;
  float* Yt = Tt + TSZ;
  __bf16* M = (__bf16*)(Yt + GSZ);

  k1_gram<<<dim3(nchunk, NB), 256, 0, stream>>>(x, gpart, NTOK / nchunk);
  k2a_reduce<<<dim3(576), 256, 0, stream>>>(gpart, G, nchunk);
  k2b1_t<<<dim3(6, NB), 256, 0, stream>>>(G, wqkv, Tt);
  k2b2_attn<<<dim3(NH, NB), 256, 0, stream>>>(Tt, wqkv, temp, Yt);
  k2c_m<<<dim3(3, NB), 256, 0, stream>>>(wproj, Yt, M);
  k3_out<<<dim3(64, NB), 256, 0, stream>>>(x, M, bproj, out);
}

// Round 2
// 232.614 us; speedup vs baseline: 1.9566x; 1.9566x over previous
//
#include <hip/hip_runtime.h>
#include <hip/hip_bf16.h>
#include <math.h>

#define C_DIM 192
#define NTOK 16384
#define NB 16
#define NH 8
#define HD 24
#define EPSN 1e-12f

typedef float f32x4 __attribute__((ext_vector_type(4)));
typedef __bf16 bf16x4 __attribute__((ext_vector_type(4)));
typedef __bf16 bf16x8 __attribute__((ext_vector_type(8)));

__device__ __forceinline__ f32x4 mfma16(bf16x8 a, bf16x8 b, f32x4 c) {
  return __builtin_amdgcn_mfma_f32_16x16x32_bf16(a, b, c, 0, 0, 0);
}

// load 8 consecutive f32 (16B-aligned x2) and convert to 8 bf16
__device__ __forceinline__ bf16x8 cvt8(const float* __restrict__ p) {
  f32x4 a = *(const f32x4*)p;
  f32x4 b = *(const f32x4*)(p + 4);
  bf16x8 r;
  r[0] = (__bf16)a[0]; r[1] = (__bf16)a[1]; r[2] = (__bf16)a[2]; r[3] = (__bf16)a[3];
  r[4] = (__bf16)b[0]; r[5] = (__bf16)b[1]; r[6] = (__bf16)b[2]; r[7] = (__bf16)b[3];
  return r;
}

// ---------------- K1: partial Gram via LDS-staged bf16 chunks ---------------
// x chunk [192 rows][32 k] staged once per block (201MB total fetch), dbuf.
__global__ __launch_bounds__(256, 2) void k1_gram(const float* __restrict__ x,
                                                  float* __restrict__ gpart,
                                                  int kc) {
  const int b = blockIdx.y, chunk = blockIdx.x;
  const float* xb = x + (size_t)b * C_DIM * NTOK + (size_t)chunk * kc;
  __shared__ __bf16 xsh[2][C_DIM * 32];  // 2 x 12KB
  const int t = threadIdx.x;
  const int lane = t & 63, wid = t >> 6;
  const int lrow = lane & 15, loct = lane >> 4;
  const int r0 = (wid >> 1) * 96, c0 = (wid & 1) * 96;
  f32x4 acc[6][6] = {};
  f32x4 stg[6];

  // prologue: stage chunk ks=0 into buf 0
#pragma unroll
  for (int it = 0; it < 6; ++it) {
    int idx = it * 256 + t, r = idx >> 3, c8 = idx & 7;
    stg[it] = *(const f32x4*)(xb + (size_t)r * NTOK + 4 * c8);
  }
#pragma unroll
  for (int it = 0; it < 6; ++it) {
    int idx = it * 256 + t, r = idx >> 3, c8 = idx & 7;
    bf16x4 w;
    w[0] = (__bf16)stg[it][0]; w[1] = (__bf16)stg[it][1];
    w[2] = (__bf16)stg[it][2]; w[3] = (__bf16)stg[it][3];
    *(bf16x4*)(&xsh[0][r * 32 + 4 * c8]) = w;
  }
  __syncthreads();

  for (int ks = 0; ks < kc; ks += 32) {
    const int cur = (ks >> 5) & 1;
    const bool more = (ks + 32) < kc;
    if (more) {
#pragma unroll
      for (int it = 0; it < 6; ++it) {
        int idx = it * 256 + t, r = idx >> 3, c8 = idx & 7;
        stg[it] = *(const f32x4*)(xb + (size_t)r * NTOK + ks + 32 + 4 * c8);
      }
    }
    bf16x8 fa[6];
#pragma unroll
    for (int i = 0; i < 6; ++i)
      fa[i] = *(const bf16x8*)(&xsh[cur][(r0 + 16 * i + lrow) * 32 + 8 * loct]);
#pragma unroll
    for (int j = 0; j < 6; ++j) {
      bf16x8 fb = *(const bf16x8*)(&xsh[cur][(c0 + 16 * j + lrow) * 32 + 8 * loct]);
#pragma unroll
      for (int i = 0; i < 6; ++i) acc[i][j] = mfma16(fa[i], fb, acc[i][j]);
    }
    if (more) {
#pragma unroll
      for (int it = 0; it < 6; ++it) {
        int idx = it * 256 + t, r = idx >> 3, c8 = idx & 7;
        bf16x4 w;
        w[0] = (__bf16)stg[it][0]; w[1] = (__bf16)stg[it][1];
        w[2] = (__bf16)stg[it][2]; w[3] = (__bf16)stg[it][3];
        *(bf16x4*)(&xsh[cur ^ 1][r * 32 + 4 * c8]) = w;
      }
    }
    __syncthreads();
  }
  float* gp = gpart + ((size_t)chunk * NB + b) * C_DIM * C_DIM;
#pragma unroll
  for (int i = 0; i < 6; ++i)
#pragma unroll
    for (int j = 0; j < 6; ++j)
#pragma unroll
      for (int e = 0; e < 4; ++e)
        gp[(size_t)(r0 + 16 * i + 4 * loct + e) * C_DIM + (c0 + 16 * j + lrow)] =
            acc[i][j][e];
}

// ---------------- K2a: reduce partials -> G ---------------------------------
__global__ __launch_bounds__(256) void k2a_reduce(const float* __restrict__ gpart,
                                                  float* __restrict__ G,
                                                  int nchunk) {
  const size_t total = (size_t)NB * C_DIM * C_DIM;
  size_t e0 = ((size_t)blockIdx.x * 256 + threadIdx.x) * 4;
  f32x4 s = {};
  for (int c = 0; c < nchunk; ++c) s += *(const f32x4*)(gpart + c * total + e0);
  *(f32x4*)(G + e0) = s;
}

// ---------------- K2b1: Tt[b] = [Wq|Wk]^T @ G  (384x192), uses G symmetry ---
__global__ __launch_bounds__(256) void k2b1_t(const float* __restrict__ G,
                                              const float* __restrict__ wqkv,
                                              float* __restrict__ Tt) {
  const int b = blockIdx.y, rb = blockIdx.x;  // rb 0..5 -> 64 rows
  const int lane = threadIdx.x & 63, wid = threadIdx.x >> 6;
  const int lrow = lane & 15, loct = lane >> 4;
  const float* Gb = G + (size_t)b * C_DIM * C_DIM;
  const int ddA = rb * 64 + wid * 16 + lrow;  // < 384, == wqkv column index
  f32x4 acc[12] = {};
  for (int s = 0; s < 6; ++s) {
    bf16x8 fa;
#pragma unroll
    for (int e = 0; e < 8; ++e)
      fa[e] = (__bf16)wqkv[(size_t)(32 * s + 8 * loct + e) * 576 + ddA];
#pragma unroll
    for (int j = 0; j < 12; ++j) {
      bf16x8 fb = cvt8(Gb + (size_t)(16 * j + lrow) * C_DIM + 32 * s + 8 * loct);
      acc[j] = mfma16(fa, fb, acc[j]);
    }
  }
  float* To = Tt + (size_t)b * 384 * C_DIM;
#pragma unroll
  for (int j = 0; j < 12; ++j)
#pragma unroll
    for (int e = 0; e < 4; ++e)
      To[(size_t)(rb * 64 + wid * 16 + 4 * loct + e) * C_DIM + 16 * j + lrow] =
          acc[j][e];
}

// ---------------- K2b2: per (b,h): S, norms, softmax, Yt -------------------
__global__ __launch_bounds__(256) void k2b2_attn(const float* __restrict__ Tt,
                                                 const float* __restrict__ wqkv,
                                                 const float* __restrict__ temp,
                                                 float* __restrict__ Yt) {
  const int b = blockIdx.y, h = blockIdx.x;
  __shared__ float SL[32][33];
  __shared__ float qn2L[HD], kn2L[HD];
  const int t = threadIdx.x;
  const int lane = t & 63, wid = t >> 6;
  const int lrow = lane & 15, loct = lane >> 4;
  const float* Tb = Tt + (size_t)b * 384 * C_DIM;
  const int r = wid >> 1, j = wid & 1;  // 2x2 tiles cover 32x32 (clip to 24x24)
  f32x4 acc = {};
  for (int s = 0; s < 6; ++s) {
    bf16x8 fa = cvt8(Tb + (size_t)(h * HD + 16 * r + lrow) * C_DIM + 32 * s + 8 * loct);
    bf16x8 fb;
#pragma unroll
    for (int e = 0; e < 8; ++e)
      fb[e] = (__bf16)wqkv[(size_t)(32 * s + 8 * loct + e) * 576 + 192 + h * HD +
                           16 * j + lrow];
    acc = mfma16(fa, fb, acc);
  }
#pragma unroll
  for (int e = 0; e < 4; ++e) {
    int d = 16 * r + 4 * loct + e, ee = 16 * j + lrow;
    if (d < HD && ee < HD) SL[d][ee] = acc[e];
  }
  if (t < 48) {  // squared norms: diag of Wq^T G Wq / Wk^T G Wk
    const int dd = (t < 24) ? t : t - 24;
    const int row = ((t < 24) ? 0 : 192) + h * HD + dd;
    float s = 0.f;
    for (int c = 0; c < C_DIM; ++c)
      s += Tb[(size_t)row * C_DIM + c] * wqkv[(size_t)c * 576 + row];
    if (t < 24) qn2L[dd] = s; else kn2L[dd] = s;
  }
  __syncthreads();
  if (t < HD) {  // softmax row t
    const float tp = temp[h];
    float nq = fmaxf(sqrtf(fmaxf(qn2L[t], 0.f)), EPSN);
    float lg[HD];
    float m = -1e30f;
#pragma unroll
    for (int e = 0; e < HD; ++e) {
      float nk = fmaxf(sqrtf(fmaxf(kn2L[e], 0.f)), EPSN);
      lg[e] = SL[t][e] / (nq * nk) * tp;
      m = fmaxf(m, lg[e]);
    }
    float sum = 0.f;
#pragma unroll
    for (int e = 0; e < HD; ++e) { lg[e] = __expf(lg[e] - m); sum += lg[e]; }
    float inv = 1.f / sum;
#pragma unroll
    for (int e = 0; e < HD; ++e) SL[t][e] = lg[e] * inv;
  }
  __syncthreads();
  if (t < C_DIM) {  // Yt[b][ci=t][h*24+d] = sum_e attn[d][e] * Wv[t][e]
    float wv[HD];
#pragma unroll
    for (int e = 0; e < HD; ++e)
      wv[e] = wqkv[(size_t)t * 576 + 384 + h * HD + e];
    float* Yo = Yt + ((size_t)b * C_DIM + t) * C_DIM + h * HD;
#pragma unroll
    for (int d = 0; d < HD; ++d) {
      float y = 0.f;
#pragma unroll
      for (int e = 0; e < HD; ++e) y += SL[d][e] * wv[e];
      Yo[d] = y;
    }
  }
}

// ---------------- K2c: M[b] = Wproj^T @ Y  (bf16 out) -----------------------
__global__ __launch_bounds__(256) void k2c_m(const float* __restrict__ wproj,
                                             const float* __restrict__ Yt,
                                             __bf16* __restrict__ M) {
  const int b = blockIdx.y, rb = blockIdx.x;  // rb 0..2 -> 64 rows
  const int lane = threadIdx.x & 63, wid = threadIdx.x >> 6;
  const int lrow = lane & 15, loct = lane >> 4;
  const float* Yb = Yt + (size_t)b * C_DIM * C_DIM;
  const int coA = rb * 64 + wid * 16 + lrow;
  f32x4 acc[12] = {};
  for (int s = 0; s < 6; ++s) {
    bf16x8 fa;
#pragma unroll
    for (int e = 0; e < 8; ++e)
      fa[e] = (__bf16)wproj[(size_t)(32 * s + 8 * loct + e) * C_DIM + coA];
#pragma unroll
    for (int j = 0; j < 12; ++j) {
      bf16x8 fb = cvt8(Yb + (size_t)(16 * j + lrow) * C_DIM + 32 * s + 8 * loct);
      acc[j] = mfma16(fa, fb, acc[j]);
    }
  }
  __bf16* Mo = M + (size_t)b * C_DIM * C_DIM;
#pragma unroll
  for (int j = 0; j < 12; ++j)
#pragma unroll
    for (int e = 0; e < 4; ++e)
      Mo[(size_t)(rb * 64 + wid * 16 + 4 * loct + e) * C_DIM + 16 * j + lrow] =
          (__bf16)acc[j][e];
}

// ---------------- K3: out[b] = M[b] @ x[b] + bias (half-M per block) --------
// 96 M-rows/block -> 36KB LDS -> 4 blocks/CU @ launch_bounds(256,4) = 50% occ.
__global__ __launch_bounds__(256, 4) void k3_out(const float* __restrict__ x,
                                                 const __bf16* __restrict__ M,
                                                 const float* __restrict__ bproj,
                                                 float* __restrict__ out) {
  const int nt = blockIdx.x, half = blockIdx.y, b = blockIdx.z;
  const int rbase = half * 96;
  __shared__ __bf16 Ml[96 * C_DIM];  // 36864B, 16B-chunk XOR swizzle
  __shared__ float biasL[96];
  const __bf16* Mb = M + (size_t)b * C_DIM * C_DIM + (size_t)rbase * C_DIM;
  for (int i = threadIdx.x; i < 96 * 24; i += 256) {
    int row = i / 24, ch = i % 24;
    bf16x8 v = *(const bf16x8*)(Mb + row * C_DIM + ch * 8);
    *(bf16x8*)(Ml + row * C_DIM + ((ch ^ (row & 7)) * 8)) = v;
  }
  if (threadIdx.x < 96) biasL[threadIdx.x] = bproj[rbase + threadIdx.x];
  __syncthreads();
  const int lane = threadIdx.x & 63, wid = threadIdx.x >> 6;
  const int lrow = lane & 15, loct = lane >> 4;
  const float* xb = x + (size_t)b * C_DIM * NTOK;
  float* ob = out + (size_t)b * C_DIM * NTOK;
  const int n0 = nt * 128 + wid * 32;
  f32x4 acc[6][2] = {};
#pragma unroll
  for (int s = 0; s < 6; ++s) {
    bf16x8 fb0, fb1;
#pragma unroll
    for (int e = 0; e < 8; ++e) {
      size_t rowoff = (size_t)(32 * s + 8 * loct + e) * NTOK;
      fb0[e] = (__bf16)xb[rowoff + n0 + lrow];
      fb1[e] = (__bf16)xb[rowoff + n0 + 16 + lrow];
    }
#pragma unroll
    for (int tt = 0; tt < 6; ++tt) {
      int rowb = 16 * tt + lrow;
      bf16x8 fa = *(const bf16x8*)(Ml + rowb * C_DIM +
                                   (((4 * s + loct) ^ (rowb & 7)) * 8));
      acc[tt][0] = mfma16(fa, fb0, acc[tt][0]);
      acc[tt][1] = mfma16(fa, fb1, acc[tt][1]);
    }
  }
#pragma unroll
  for (int tt = 0; tt < 6; ++tt) {
    const int rw = 16 * tt + 4 * loct;
    f32x4 bias = *(const f32x4*)(biasL + rw);
#pragma unroll
    for (int e = 0; e < 4; ++e) {
      ob[(size_t)(rbase + rw + e) * NTOK + n0 + lrow] = acc[tt][0][e] + bias[e];
      ob[(size_t)(rbase + rw + e) * NTOK + n0 + 16 + lrow] = acc[tt][1][e] + bias[e];
    }
  }
}

extern "C" void kernel_launch(void* const* d_in, const int* in_sizes, int n_in,
                              void* d_out, int out_size, void* d_ws, size_t ws_size,
                              hipStream_t stream) {
  const float* x = (const float*)d_in[0];
  const float* wqkv = (const float*)d_in[1];
  const float* wproj = (const float*)d_in[2];
  const float* bproj = (const float*)d_in[3];
  const float* temp = (const float*)d_in[4];
  float* out = (float*)d_out;

  const size_t GSZ = (size_t)NB * C_DIM * C_DIM;  // 589824 floats
  const size_t TSZ = (size_t)NB * 384 * C_DIM;    // 1179648 floats
  int nchunk = 32;
  while (nchunk > 1 &&
         ((size_t)nchunk * GSZ + GSZ + TSZ + GSZ + GSZ) * 4 > ws_size)
    nchunk >>= 1;
  float* wsf = (float*)d_ws;
  float* gpart = wsf;
  float* G = gpart + (size_t)nchunk * GSZ;
  float* Tt = G + GSZ;
  float* Yt = Tt + TSZ;
  __bf16* M = (__bf16*)(Yt + GSZ);

  k1_gram<<<dim3(nchunk, NB), 256, 0, stream>>>(x, gpart, NTOK / nchunk);
  k2a_reduce<<<dim3(576), 256, 0, stream>>>(gpart, G, nchunk);
  k2b1_t<<<dim3(6, NB), 256, 0, stream>>>(G, wqkv, Tt);
  k2b2_attn<<<dim3(NH, NB), 256, 0, stream>>>(Tt, wqkv, temp, Yt);
  k2c_m<<<dim3(3, NB), 256, 0, stream>>>(wproj, Yt, M);
  k3_out<<<dim3(128, 2, NB), 256, 0, stream>>>(x, M, bproj, out);
}